// Round 8
// baseline (186.863 us; speedup 1.0000x reference)
//
#include <hip/hip_runtime.h>
#include <hip/hip_bf16.h>

typedef unsigned short u16;
typedef unsigned int u32;
typedef __attribute__((ext_vector_type(8))) __bf16 bf16x8;
typedef __attribute__((ext_vector_type(4))) float f32x4;
typedef __attribute__((ext_vector_type(16))) float f32x16;
typedef __attribute__((ext_vector_type(2))) unsigned u32x2;

// f32 -> bf16 round-to-nearest-even
__device__ __forceinline__ u16 f2bf(float f) {
  u32 u = __builtin_bit_cast(u32, f);
  return (u16)((u + 0x7fffu + ((u >> 16) & 1u)) >> 16);
}
__device__ __forceinline__ float bf2f(u16 h) {
  u32 u = ((u32)h) << 16;
  return __builtin_bit_cast(float, u);
}
// pack two floats to bf16x2 word
__device__ __forceinline__ u32 pk2(float lo, float hi) {
  union { __bf16 b[2]; u32 u; } r;
  r.b[0] = (__bf16)lo; r.b[1] = (__bf16)hi;
  return r.u;
}

// permlane32_swap intrinsic wrapper (round-5 post-mortem: never raw asm with
// "+v","+v" on same-value operands — allocator may merge them).
__device__ __forceinline__ void pl32pair(u32& a, u32& b) {
#if __has_builtin(__builtin_amdgcn_permlane32_swap)
  u32x2 r = __builtin_amdgcn_permlane32_swap(a, b, 0, 0);
  a = r.x; b = r.y;
#else
  int hi = (int)((threadIdx.x & 63) >> 5);
  u32 as = __shfl_xor(a, 32), bs = __shfl_xor(b, 32);
  u32 na = hi ? bs : a;
  u32 nb = hi ? b : as;
  a = na; b = nb;
#endif
}
__device__ __forceinline__ float red_max32(float x) {
  u32 a = __builtin_bit_cast(u32, x), b = __builtin_bit_cast(u32, x);
  pl32pair(a, b);
  return fmaxf(__builtin_bit_cast(float, a), __builtin_bit_cast(float, b));
}
__device__ __forceinline__ float red_sum32(float x) {
  u32 a = __builtin_bit_cast(u32, x), b = __builtin_bit_cast(u32, x);
  pl32pair(a, b);
  return __builtin_bit_cast(float, a) + __builtin_bit_cast(float, b);
}

// ---------------- cast x: fp32 -> bf16, 8 elems/thread ----------------
__global__ __launch_bounds__(256) void cast_x_kernel(const float* __restrict__ x,
                                                     u16* __restrict__ xb) {
  size_t i = ((size_t)blockIdx.x * 256 + threadIdx.x) * 8;
  float4 a = *(const float4*)(x + i);
  float4 b = *(const float4*)(x + i + 4);
  union { u16 h[8]; uint4 v; } o;
  o.h[0] = f2bf(a.x); o.h[1] = f2bf(a.y); o.h[2] = f2bf(a.z); o.h[3] = f2bf(a.w);
  o.h[4] = f2bf(b.x); o.h[5] = f2bf(b.y); o.h[6] = f2bf(b.z); o.h[7] = f2bf(b.w);
  *(uint4*)(xb + i) = o.v;
}

// ---------- cast + transpose W: [2048][256] f32 -> Wbt[768][2048] bf16 ----------
__global__ void cast_w_kernel(const float* __restrict__ Wq, const float* __restrict__ Wk,
                              const float* __restrict__ Wv, u16* __restrict__ wbt) {
  __shared__ float tile[32][33];
  int e0 = blockIdx.x * 32, d0 = blockIdx.y * 32, w = blockIdx.z;
  const float* W = (w == 0) ? Wq : ((w == 1) ? Wk : Wv);
  int x = threadIdx.x, y = threadIdx.y;
#pragma unroll
  for (int j = 0; j < 4; j++)
    tile[y + j * 8][x] = W[(size_t)(e0 + y + j * 8) * 256 + d0 + x];
  __syncthreads();
#pragma unroll
  for (int j = 0; j < 4; j++)
    wbt[(size_t)(w * 256 + d0 + y + j * 8) * 2048 + e0 + x] = f2bf(tile[x][y + j * 8]);
}

// ------------- GEMM v2: phase-split, counted-vmcnt, 3-buffer rotation -------------
__global__ __launch_bounds__(512, 2) void gemm_kernel(const u16* __restrict__ A,
                                                      const u16* __restrict__ Bt,
                                                      u16* __restrict__ C) {
  __shared__ __align__(16) u16 As[3][8192];
  __shared__ __align__(16) u16 Bs[3][8192];

  int tid = threadIdx.x;
  int w = tid >> 6, l = tid & 63;
  int lr = l & 15, lg = l >> 4;
  int wr = w >> 2, wc = w & 3;

  int bid = blockIdx.x;
  int vid = (bid & 7) * 24 + (bid >> 3);
  int colb = vid >> 6, rowb = vid & 63;
  int row0 = rowb * 256, col0 = colb * 256;

  int srow = w * 16 + (l >> 2);
  int scol = ((l & 3) * 8) ^ (((l >> 2) & 3) * 8);
  const u16* ga = A + (size_t)(row0 + srow) * 2048 + scol;
  const u16* gb = Bt + (size_t)(col0 + srow) * 2048 + scol;

  f32x4 acc[8][4];
#pragma unroll
  for (int m = 0; m < 8; m++)
#pragma unroll
    for (int n = 0; n < 4; n++) acc[m][n] = (f32x4){0.f, 0.f, 0.f, 0.f};

  int rcol = (lg * 8) ^ ((lr & 3) * 8);

#define STAGE_A(ts, bi)                                                               \
  {                                                                                   \
    _Pragma("unroll") for (int c = 0; c < 2; c++)                                     \
        __builtin_amdgcn_global_load_lds(                                             \
            (const __attribute__((address_space(1))) void*)(ga + (size_t)c * 128 * 2048 + (ts) * 32), \
            (__attribute__((address_space(3))) void*)&As[bi][c * 4096 + w * 512], 16, 0, 0); \
  }
#define STAGE_B(ts, bi)                                                               \
  {                                                                                   \
    _Pragma("unroll") for (int c = 0; c < 2; c++)                                     \
        __builtin_amdgcn_global_load_lds(                                             \
            (const __attribute__((address_space(1))) void*)(gb + (size_t)c * 128 * 2048 + (ts) * 32), \
            (__attribute__((address_space(3))) void*)&Bs[bi][c * 4096 + w * 512], 16, 0, 0); \
  }

  STAGE_A(0, 0); STAGE_B(0, 0);
  STAGE_A(1, 1); STAGE_B(1, 1);
  asm volatile("s_waitcnt vmcnt(4)" ::: "memory");
  __builtin_amdgcn_s_barrier();

  int bi = 0, bp = 2;
  for (int t = 0; t < 64; t++) {
    int ts = (t + 2 <= 63) ? (t + 2) : 63;
    const u16* asb = As[bi];
    const u16* bsb = Bs[bi];

    bf16x8 bfr[4], af[4];
#pragma unroll
    for (int n = 0; n < 4; n++)
      bfr[n] = *(const bf16x8*)&bsb[(wc * 64 + n * 16 + lr) * 32 + rcol];
#pragma unroll
    for (int m = 0; m < 4; m++)
      af[m] = *(const bf16x8*)&asb[(wr * 128 + m * 16 + lr) * 32 + rcol];
    STAGE_A(ts, bp);
    __builtin_amdgcn_s_barrier();
    asm volatile("s_waitcnt lgkmcnt(0)" ::: "memory");
    __builtin_amdgcn_sched_barrier(0);
    __builtin_amdgcn_s_setprio(1);
#pragma unroll
    for (int m = 0; m < 4; m++)
#pragma unroll
      for (int n = 0; n < 4; n++)
        acc[m][n] = __builtin_amdgcn_mfma_f32_16x16x32_bf16(af[m], bfr[n], acc[m][n], 0, 0, 0);
    __builtin_amdgcn_s_setprio(0);
    __builtin_amdgcn_s_barrier();

    bf16x8 af2[4];
#pragma unroll
    for (int m = 0; m < 4; m++)
      af2[m] = *(const bf16x8*)&asb[(wr * 128 + (m + 4) * 16 + lr) * 32 + rcol];
    STAGE_B(ts, bp);
    asm volatile("s_waitcnt vmcnt(4)" ::: "memory");
    __builtin_amdgcn_s_barrier();
    asm volatile("s_waitcnt lgkmcnt(0)" ::: "memory");
    __builtin_amdgcn_sched_barrier(0);
    __builtin_amdgcn_s_setprio(1);
#pragma unroll
    for (int m = 0; m < 4; m++)
#pragma unroll
      for (int n = 0; n < 4; n++)
        acc[m + 4][n] = __builtin_amdgcn_mfma_f32_16x16x32_bf16(af2[m], bfr[n], acc[m + 4][n], 0, 0, 0);
    __builtin_amdgcn_s_setprio(0);
    __builtin_amdgcn_s_barrier();

    bi = (bi == 2) ? 0 : bi + 1;
    bp = (bp == 2) ? 0 : bp + 1;
  }
#undef STAGE_A
#undef STAGE_B

  int crow = row0 + wr * 128;
  int ccol = col0 + wc * 64 + lr;
#pragma unroll
  for (int m = 0; m < 8; m++)
#pragma unroll
    for (int n = 0; n < 4; n++)
#pragma unroll
      for (int i = 0; i < 4; i++)
        C[(size_t)(crow + m * 16 + lg * 4 + i) * 768 + ccol + n * 16] = f2bf(acc[m][n][i]);
}

// -------- K -> swapped-A-frag order for mfma_32x32x16 --------
__global__ __launch_bounds__(256) void kfrag_kernel(const u16* __restrict__ qkv,
                                                    u16* __restrict__ kfrag) {
  __shared__ __align__(16) u16 tile[32 * 264];
  int t = threadIdx.x, kvb = blockIdx.x, b = blockIdx.y;
#pragma unroll
  for (int c = 0; c < 4; c++) {
    int m = c * 256 + t;
    int r = m >> 5, c16 = m & 31;
    bf16x8 v = *(const bf16x8*)(qkv + (size_t)(b * 2048 + kvb * 32 + r) * 768 + 256 + c16 * 8);
    *(bf16x8*)&tile[r * 264 + c16 * 8] = v;
  }
  __syncthreads();
#pragma unroll
  for (int c = 0; c < 4; c++) {
    int m = c * 256 + t;
    int t16 = m >> 6, l = m & 63;
    bf16x8 v = *(const bf16x8*)&tile[(l & 31) * 264 + t16 * 16 + (l >> 5) * 8];
    *(bf16x8*)(kfrag + ((size_t)((b * 64 + kvb) * 16 + t16) * 64 + l) * 8) = v;
  }
}

// -------- V -> V^T A-frag order for PV mfma_32x32x16 --------
__global__ __launch_bounds__(256) void vfrag_kernel(const u16* __restrict__ qkv,
                                                    u16* __restrict__ vfrag) {
  __shared__ __align__(16) u16 tile[32 * 264];
  int t = threadIdx.x, kvb = blockIdx.x, b = blockIdx.y;
#pragma unroll
  for (int c = 0; c < 4; c++) {
    int m = c * 256 + t;
    int r = m >> 5, c16 = m & 31;
    bf16x8 v = *(const bf16x8*)(qkv + (size_t)(b * 2048 + kvb * 32 + r) * 768 + 512 + c16 * 8);
    *(bf16x8*)&tile[r * 264 + c16 * 8] = v;
  }
  __syncthreads();
#pragma unroll
  for (int c = 0; c < 4; c++) {
    int m = c * 256 + t;
    int ch = m >> 9, dblk = (m >> 6) & 7, l = m & 63;
    union { u16 h[8]; uint4 v; } o;
#pragma unroll
    for (int j = 0; j < 8; j++)
      o.h[j] = tile[(ch * 16 + (l >> 5) * 8 + j) * 264 + dblk * 32 + (l & 31)];
    *(uint4*)(vfrag + ((size_t)(((b * 64 + kvb) * 2 + ch) * 8 + dblk) * 64 + l) * 8) = o.v;
  }
}

// ---------------- flash attention v7: spill-free (Q in LDS, streamed K/V) ----------------
// v6 structure (tile-pair, 8 waves split KV stride-8, in-lane softmax,
// permlane exchanges, defer-max, facc merge) with register-pressure fixes:
//  - Q B-frags staged ONCE per tile into LDS (identical across all 8 waves);
//    read per-MFMA via conflict-free ds_read_b128. Frees 64 persistent VGPRs.
//  - K streamed in 4 groups of 4 frags (<=16 live regs, was 64).
//  - V split: 8 frags (B0 operands) issued pre-softmax, 8 loaded in PV loop.
// Target: zero scratch (round-7 counters showed ~70 MB/dispatch spill traffic).
__global__ __launch_bounds__(512, 2) void attn_kernel(const u16* __restrict__ qkv,
                                                      const u16* __restrict__ kfrag,
                                                      const u16* __restrict__ vfrag,
                                                      float* __restrict__ out) {
  __shared__ __align__(16) u16 qlds[16 * 512];  // [t16][lane][8], pre-scaled 1/256
  __shared__ float facc[32][264];
  __shared__ float sm[8][32];
  __shared__ float sl[8][32];

  int tid = threadIdx.x;
  int w = tid >> 6, l = tid & 63;
  int ql = l & 31, hi = l >> 5;
  int bid = blockIdx.x;
  int b = bid & 7;
  int p = bid >> 3;

  for (int tile = 0; tile < 2; tile++) {
    int jt = tile ? p : (63 - p);
    int q0 = jt * 32;

    // ---- stage Q B-frags (scaled) into LDS: 1024 frags, 512 threads x 2 ----
    if (tile) __syncthreads();  // tile-0 normalize readers done before qlds overwrite
#pragma unroll
    for (int c = 0; c < 2; c++) {
      int m = c * 512 + tid;
      int t16 = m >> 6, ll = m & 63;
      const u16* src = qkv + (size_t)(b * 2048 + q0 + (ll & 31)) * 768 + t16 * 16 + (ll >> 5) * 8;
      union { u16 h[8]; bf16x8 v; } in, ov;
      in.v = *(const bf16x8*)src;
#pragma unroll
      for (int j = 0; j < 8; j++) ov.h[j] = f2bf(bf2f(in.h[j]) * (1.0f / 256.0f));
      *(bf16x8*)&qlds[(t16 * 64 + ll) * 8] = ov.v;
    }
    __syncthreads();

    f32x16 o[8];
#pragma unroll
    for (int d = 0; d < 8; d++)
#pragma unroll
      for (int r = 0; r < 16; r++) o[d][r] = 0.f;
    float mreg = -__builtin_inff(), ell = 0.f;

    for (int jb = w; jb <= jt; jb += 8) {
      const u16* kb = kfrag + ((size_t)(b * 64 + jb) * 16 * 64 + l) * 8;
      const u16* vb = vfrag + ((size_t)(b * 64 + jb) * 16 * 64 + l) * 8;

      // ---- QK^T: K streamed in 4 groups of 4; Q from LDS per MFMA ----
      f32x16 sA, sB;
#pragma unroll
      for (int r = 0; r < 16; r++) { sA[r] = 0.f; sB[r] = 0.f; }
#pragma unroll
      for (int g = 0; g < 4; g++) {
        bf16x8 k0 = *(const bf16x8*)(kb + (g * 4 + 0) * 512);
        bf16x8 k1 = *(const bf16x8*)(kb + (g * 4 + 1) * 512);
        bf16x8 k2 = *(const bf16x8*)(kb + (g * 4 + 2) * 512);
        bf16x8 k3 = *(const bf16x8*)(kb + (g * 4 + 3) * 512);
        bf16x8 q0f = *(const bf16x8*)&qlds[((g * 4 + 0) * 64 + l) * 8];
        bf16x8 q1f = *(const bf16x8*)&qlds[((g * 4 + 1) * 64 + l) * 8];
        bf16x8 q2f = *(const bf16x8*)&qlds[((g * 4 + 2) * 64 + l) * 8];
        bf16x8 q3f = *(const bf16x8*)&qlds[((g * 4 + 3) * 64 + l) * 8];
        sA = __builtin_amdgcn_mfma_f32_32x32x16_bf16(k0, q0f, sA, 0, 0, 0);
        sB = __builtin_amdgcn_mfma_f32_32x32x16_bf16(k1, q1f, sB, 0, 0, 0);
        sA = __builtin_amdgcn_mfma_f32_32x32x16_bf16(k2, q2f, sA, 0, 0, 0);
        sB = __builtin_amdgcn_mfma_f32_32x32x16_bf16(k3, q3f, sB, 0, 0, 0);
      }

      // ---- first 8 V frags (B0 operands) issued early: overlap softmax ----
      bf16x8 ve[8];
#pragma unroll
      for (int i = 0; i < 8; i++) ve[i] = *(const bf16x8*)(vb + i * 512);

      float s[16];
#pragma unroll
      for (int r = 0; r < 16; r++) s[r] = sA[r] + sB[r];

      // causal mask (diagonal tile); lane's kv for reg r: (r&3)+8*(r>>2)+4*hi
      if (jb == jt) {
#pragma unroll
        for (int r = 0; r < 16; r++) {
          int kv = (r & 3) + 8 * (r >> 2) + 4 * hi;
          if (kv > ql) s[r] = -__builtin_inff();
        }
      }

      // ---- in-lane online softmax; cross-half via permlane32_swap ----
      float mx = s[0];
#pragma unroll
      for (int r = 1; r < 16; r++) mx = fmaxf(mx, s[r]);
      mx = red_max32(mx);
      if (__any(mx > mreg + 8.f)) {
        float mnew = fmaxf(mreg, mx);
        float sf = __expf(mreg - mnew);
        mreg = mnew;
        ell *= sf;
#pragma unroll
        for (int d = 0; d < 8; d++)
#pragma unroll
          for (int r = 0; r < 16; r++) o[d][r] *= sf;
      }
      float pr[16], ps = 0.f;
#pragma unroll
      for (int r = 0; r < 16; r++) { pr[r] = __expf(s[r] - mreg); ps += pr[r]; }
      ell += red_sum32(ps);

      // ---- pack P -> bf16 words; 4 permlane swaps build both B-frags ----
      u32 wv[8];
#pragma unroll
      for (int i = 0; i < 8; i++) wv[i] = pk2(pr[2 * i], pr[2 * i + 1]);
      pl32pair(wv[0], wv[2]); pl32pair(wv[1], wv[3]);
      pl32pair(wv[4], wv[6]); pl32pair(wv[5], wv[7]);
      union { u32 u[4]; bf16x8 v; } B0, B1;
      B0.u[0] = wv[0]; B0.u[1] = wv[1]; B0.u[2] = wv[2]; B0.u[3] = wv[3];
      B1.u[0] = wv[4]; B1.u[1] = wv[5]; B1.u[2] = wv[6]; B1.u[3] = wv[7];

      // ---- PV: second-half V loaded in-loop (pipelined) ----
#pragma unroll
      for (int d = 0; d < 8; d++) {
        bf16x8 v1 = *(const bf16x8*)(vb + (8 + d) * 512);
        o[d] = __builtin_amdgcn_mfma_f32_32x32x16_bf16(ve[d], B0.v, o[d], 0, 0, 0);
        o[d] = __builtin_amdgcn_mfma_f32_32x32x16_bf16(v1, B1.v, o[d], 0, 0, 0);
      }
    }

    // ---- merge across 8 waves ----
    __syncthreads();
    if (l < 32) { sm[w][l] = mreg; sl[w][l] = ell; }
    __syncthreads();

    float M = sm[0][ql];
#pragma unroll
    for (int ww = 1; ww < 8; ww++) M = fmaxf(M, sm[ww][ql]);
    float alpha = __expf(mreg - M);

#pragma unroll
    for (int ww = 0; ww < 8; ww++) {
      if (w == ww) {
#pragma unroll
        for (int d = 0; d < 8; d++)
#pragma unroll
          for (int rq = 0; rq < 4; rq++) {
            int base = d * 32 + 8 * rq + 4 * hi;
            f32x4 v;
#pragma unroll
            for (int i = 0; i < 4; i++) v[i] = alpha * o[d][rq * 4 + i];
            float* fp = &facc[ql][base];
            if (ww == 0) *(f32x4*)fp = v;
            else {
              f32x4 old = *(const f32x4*)fp;
              *(f32x4*)fp = old + v;
            }
          }
      }
      __syncthreads();
    }

    // ---- normalize + coalesced write ----
    int r = tid >> 4, lt = tid & 15;
    float Mr = sm[0][r];
#pragma unroll
    for (int ww = 1; ww < 8; ww++) Mr = fmaxf(Mr, sm[ww][r]);
    float denom = 0.f;
#pragma unroll
    for (int ww = 0; ww < 8; ww++) denom += __expf(sm[ww][r] - Mr) * sl[ww][r];
    float inv = 1.0f / denom;
    float* orow = out + (size_t)(b * 2048 + q0 + r) * 256;
#pragma unroll
    for (int j = 0; j < 4; j++) {
      int c = (lt + j * 16) * 4;
      f32x4 v = *(const f32x4*)&facc[r][c];
      v[0] *= inv; v[1] *= inv; v[2] *= inv; v[3] *= inv;
      *(f32x4*)&orow[c] = v;
    }
  }
}

extern "C" void kernel_launch(void* const* d_in, const int* in_sizes, int n_in,
                              void* d_out, int out_size, void* d_ws, size_t ws_size,
                              hipStream_t stream) {
  (void)in_sizes; (void)n_in; (void)out_size; (void)ws_size;
  const float* x = (const float*)d_in[0];
  const float* Wq = (const float*)d_in[1];
  const float* Wk = (const float*)d_in[2];
  const float* Wv = (const float*)d_in[3];
  float* out = (float*)d_out;

  char* ws = (char*)d_ws;
  u16* xb  = (u16*)(ws);                    // [0, 67,108,864)
  u16* wbt = (u16*)(ws + 67108864);         // [67,108,864, 70,254,592)
  u16* qkv = (u16*)(ws + 70254592);         // [70,254,592, 95,420,416)
  u16* kfrag = (u16*)(ws);                  // aliases dead xb region
  u16* vfrag = (u16*)(ws + 8388608);

  cast_x_kernel<<<16384, 256, 0, stream>>>(x, xb);
  cast_w_kernel<<<dim3(64, 8, 3), dim3(32, 8), 0, stream>>>(Wq, Wk, Wv, wbt);
  gemm_kernel<<<192, 512, 0, stream>>>(xb, wbt, qkv);
  kfrag_kernel<<<dim3(64, 8), 256, 0, stream>>>(qkv, kfrag);
  vfrag_kernel<<<dim3(64, 8), 256, 0, stream>>>(qkv, vfrag);
  attn_kernel<<<256, 512, 0, stream>>>(qkv, kfrag, vfrag, out);
}

// Round 9
// 158.278 us; speedup vs baseline: 1.1806x; 1.1806x over previous
//
#include <hip/hip_runtime.h>
#include <hip/hip_bf16.h>

typedef unsigned short u16;
typedef unsigned int u32;
typedef __attribute__((ext_vector_type(8))) __bf16 bf16x8;
typedef __attribute__((ext_vector_type(4))) float f32x4;
typedef __attribute__((ext_vector_type(16))) float f32x16;
typedef __attribute__((ext_vector_type(2))) unsigned u32x2;

// f32 -> bf16 round-to-nearest-even
__device__ __forceinline__ u16 f2bf(float f) {
  u32 u = __builtin_bit_cast(u32, f);
  return (u16)((u + 0x7fffu + ((u >> 16) & 1u)) >> 16);
}
__device__ __forceinline__ float bf2f(u16 h) {
  u32 u = ((u32)h) << 16;
  return __builtin_bit_cast(float, u);
}
// pack two floats to bf16x2 word
__device__ __forceinline__ u32 pk2(float lo, float hi) {
  union { __bf16 b[2]; u32 u; } r;
  r.b[0] = (__bf16)lo; r.b[1] = (__bf16)hi;
  return r.u;
}

// permlane32_swap intrinsic wrapper (round-5 post-mortem: never raw asm with
// "+v","+v" on same-value operands — allocator may merge them).
__device__ __forceinline__ void pl32pair(u32& a, u32& b) {
#if __has_builtin(__builtin_amdgcn_permlane32_swap)
  u32x2 r = __builtin_amdgcn_permlane32_swap(a, b, 0, 0);
  a = r.x; b = r.y;
#else
  int hi = (int)((threadIdx.x & 63) >> 5);
  u32 as = __shfl_xor(a, 32), bs = __shfl_xor(b, 32);
  u32 na = hi ? bs : a;
  u32 nb = hi ? b : as;
  a = na; b = nb;
#endif
}
__device__ __forceinline__ float red_max32(float x) {
  u32 a = __builtin_bit_cast(u32, x), b = __builtin_bit_cast(u32, x);
  pl32pair(a, b);
  return fmaxf(__builtin_bit_cast(float, a), __builtin_bit_cast(float, b));
}
__device__ __forceinline__ float red_sum32(float x) {
  u32 a = __builtin_bit_cast(u32, x), b = __builtin_bit_cast(u32, x);
  pl32pair(a, b);
  return __builtin_bit_cast(float, a) + __builtin_bit_cast(float, b);
}

// ---------------- cast x: fp32 -> bf16, 8 elems/thread ----------------
__global__ __launch_bounds__(256) void cast_x_kernel(const float* __restrict__ x,
                                                     u16* __restrict__ xb) {
  size_t i = ((size_t)blockIdx.x * 256 + threadIdx.x) * 8;
  float4 a = *(const float4*)(x + i);
  float4 b = *(const float4*)(x + i + 4);
  union { u16 h[8]; uint4 v; } o;
  o.h[0] = f2bf(a.x); o.h[1] = f2bf(a.y); o.h[2] = f2bf(a.z); o.h[3] = f2bf(a.w);
  o.h[4] = f2bf(b.x); o.h[5] = f2bf(b.y); o.h[6] = f2bf(b.z); o.h[7] = f2bf(b.w);
  *(uint4*)(xb + i) = o.v;
}

// ---------- cast + transpose W: [2048][256] f32 -> Wbt[768][2048] bf16 ----------
__global__ void cast_w_kernel(const float* __restrict__ Wq, const float* __restrict__ Wk,
                              const float* __restrict__ Wv, u16* __restrict__ wbt) {
  __shared__ float tile[32][33];
  int e0 = blockIdx.x * 32, d0 = blockIdx.y * 32, w = blockIdx.z;
  const float* W = (w == 0) ? Wq : ((w == 1) ? Wk : Wv);
  int x = threadIdx.x, y = threadIdx.y;
#pragma unroll
  for (int j = 0; j < 4; j++)
    tile[y + j * 8][x] = W[(size_t)(e0 + y + j * 8) * 256 + d0 + x];
  __syncthreads();
#pragma unroll
  for (int j = 0; j < 4; j++)
    wbt[(size_t)(w * 256 + d0 + y + j * 8) * 2048 + e0 + x] = f2bf(tile[x][y + j * 8]);
}

// ------------- GEMM v2: phase-split, counted-vmcnt, 3-buffer rotation -------------
__global__ __launch_bounds__(512, 2) void gemm_kernel(const u16* __restrict__ A,
                                                      const u16* __restrict__ Bt,
                                                      u16* __restrict__ C) {
  __shared__ __align__(16) u16 As[3][8192];
  __shared__ __align__(16) u16 Bs[3][8192];

  int tid = threadIdx.x;
  int w = tid >> 6, l = tid & 63;
  int lr = l & 15, lg = l >> 4;
  int wr = w >> 2, wc = w & 3;

  int bid = blockIdx.x;
  int vid = (bid & 7) * 24 + (bid >> 3);
  int colb = vid >> 6, rowb = vid & 63;
  int row0 = rowb * 256, col0 = colb * 256;

  int srow = w * 16 + (l >> 2);
  int scol = ((l & 3) * 8) ^ (((l >> 2) & 3) * 8);
  const u16* ga = A + (size_t)(row0 + srow) * 2048 + scol;
  const u16* gb = Bt + (size_t)(col0 + srow) * 2048 + scol;

  f32x4 acc[8][4];
#pragma unroll
  for (int m = 0; m < 8; m++)
#pragma unroll
    for (int n = 0; n < 4; n++) acc[m][n] = (f32x4){0.f, 0.f, 0.f, 0.f};

  int rcol = (lg * 8) ^ ((lr & 3) * 8);

#define STAGE_A(ts, bi)                                                               \
  {                                                                                   \
    _Pragma("unroll") for (int c = 0; c < 2; c++)                                     \
        __builtin_amdgcn_global_load_lds(                                             \
            (const __attribute__((address_space(1))) void*)(ga + (size_t)c * 128 * 2048 + (ts) * 32), \
            (__attribute__((address_space(3))) void*)&As[bi][c * 4096 + w * 512], 16, 0, 0); \
  }
#define STAGE_B(ts, bi)                                                               \
  {                                                                                   \
    _Pragma("unroll") for (int c = 0; c < 2; c++)                                     \
        __builtin_amdgcn_global_load_lds(                                             \
            (const __attribute__((address_space(1))) void*)(gb + (size_t)c * 128 * 2048 + (ts) * 32), \
            (__attribute__((address_space(3))) void*)&Bs[bi][c * 4096 + w * 512], 16, 0, 0); \
  }

  STAGE_A(0, 0); STAGE_B(0, 0);
  STAGE_A(1, 1); STAGE_B(1, 1);
  asm volatile("s_waitcnt vmcnt(4)" ::: "memory");
  __builtin_amdgcn_s_barrier();

  int bi = 0, bp = 2;
  for (int t = 0; t < 64; t++) {
    int ts = (t + 2 <= 63) ? (t + 2) : 63;
    const u16* asb = As[bi];
    const u16* bsb = Bs[bi];

    bf16x8 bfr[4], af[4];
#pragma unroll
    for (int n = 0; n < 4; n++)
      bfr[n] = *(const bf16x8*)&bsb[(wc * 64 + n * 16 + lr) * 32 + rcol];
#pragma unroll
    for (int m = 0; m < 4; m++)
      af[m] = *(const bf16x8*)&asb[(wr * 128 + m * 16 + lr) * 32 + rcol];
    STAGE_A(ts, bp);
    __builtin_amdgcn_s_barrier();
    asm volatile("s_waitcnt lgkmcnt(0)" ::: "memory");
    __builtin_amdgcn_sched_barrier(0);
    __builtin_amdgcn_s_setprio(1);
#pragma unroll
    for (int m = 0; m < 4; m++)
#pragma unroll
      for (int n = 0; n < 4; n++)
        acc[m][n] = __builtin_amdgcn_mfma_f32_16x16x32_bf16(af[m], bfr[n], acc[m][n], 0, 0, 0);
    __builtin_amdgcn_s_setprio(0);
    __builtin_amdgcn_s_barrier();

    bf16x8 af2[4];
#pragma unroll
    for (int m = 0; m < 4; m++)
      af2[m] = *(const bf16x8*)&asb[(wr * 128 + (m + 4) * 16 + lr) * 32 + rcol];
    STAGE_B(ts, bp);
    asm volatile("s_waitcnt vmcnt(4)" ::: "memory");
    __builtin_amdgcn_s_barrier();
    asm volatile("s_waitcnt lgkmcnt(0)" ::: "memory");
    __builtin_amdgcn_sched_barrier(0);
    __builtin_amdgcn_s_setprio(1);
#pragma unroll
    for (int m = 0; m < 4; m++)
#pragma unroll
      for (int n = 0; n < 4; n++)
        acc[m + 4][n] = __builtin_amdgcn_mfma_f32_16x16x32_bf16(af2[m], bfr[n], acc[m + 4][n], 0, 0, 0);
    __builtin_amdgcn_s_setprio(0);
    __builtin_amdgcn_s_barrier();

    bi = (bi == 2) ? 0 : bi + 1;
    bp = (bp == 2) ? 0 : bp + 1;
  }
#undef STAGE_A
#undef STAGE_B

  int crow = row0 + wr * 128;
  int ccol = col0 + wc * 64 + lr;
#pragma unroll
  for (int m = 0; m < 8; m++)
#pragma unroll
    for (int n = 0; n < 4; n++)
#pragma unroll
      for (int i = 0; i < 4; i++)
        C[(size_t)(crow + m * 16 + lg * 4 + i) * 768 + ccol + n * 16] = f2bf(acc[m][n][i]);
}

// -------- K -> swapped-A-frag order for mfma_32x32x16 --------
__global__ __launch_bounds__(256) void kfrag_kernel(const u16* __restrict__ qkv,
                                                    u16* __restrict__ kfrag) {
  __shared__ __align__(16) u16 tile[32 * 264];
  int t = threadIdx.x, kvb = blockIdx.x, b = blockIdx.y;
#pragma unroll
  for (int c = 0; c < 4; c++) {
    int m = c * 256 + t;
    int r = m >> 5, c16 = m & 31;
    bf16x8 v = *(const bf16x8*)(qkv + (size_t)(b * 2048 + kvb * 32 + r) * 768 + 256 + c16 * 8);
    *(bf16x8*)&tile[r * 264 + c16 * 8] = v;
  }
  __syncthreads();
#pragma unroll
  for (int c = 0; c < 4; c++) {
    int m = c * 256 + t;
    int t16 = m >> 6, l = m & 63;
    bf16x8 v = *(const bf16x8*)&tile[(l & 31) * 264 + t16 * 16 + (l >> 5) * 8];
    *(bf16x8*)(kfrag + ((size_t)((b * 64 + kvb) * 16 + t16) * 64 + l) * 8) = v;
  }
}

// -------- V -> V^T A-frag order for PV mfma_32x32x16 --------
__global__ __launch_bounds__(256) void vfrag_kernel(const u16* __restrict__ qkv,
                                                    u16* __restrict__ vfrag) {
  __shared__ __align__(16) u16 tile[32 * 264];
  int t = threadIdx.x, kvb = blockIdx.x, b = blockIdx.y;
#pragma unroll
  for (int c = 0; c < 4; c++) {
    int m = c * 256 + t;
    int r = m >> 5, c16 = m & 31;
    bf16x8 v = *(const bf16x8*)(qkv + (size_t)(b * 2048 + kvb * 32 + r) * 768 + 512 + c16 * 8);
    *(bf16x8*)&tile[r * 264 + c16 * 8] = v;
  }
  __syncthreads();
#pragma unroll
  for (int c = 0; c < 4; c++) {
    int m = c * 256 + t;
    int ch = m >> 9, dblk = (m >> 6) & 7, l = m & 63;
    union { u16 h[8]; uint4 v; } o;
#pragma unroll
    for (int j = 0; j < 8; j++)
      o.h[j] = tile[(ch * 16 + (l >> 5) * 8 + j) * 264 + dblk * 32 + (l & 31)];
    *(uint4*)(vfrag + ((size_t)(((b * 64 + kvb) * 2 + ch) * 8 + dblk) * 64 + l) * 8) = o.v;
  }
}

// -------- flash attention v8: d-split wave pairs (64-reg accumulator) --------
// grid 256 (1 block/CU), 512 threads (8 waves). b = bid&7, p = bid>>3,
// tile pair jt = {63-p, p}. Wave w: stream = w&3 (kv blocks jb ≡ stream mod 4),
// dhalf = w>>2 (d 0..127 or 128..255). Pair (w, w+4) duplicates QK^T+softmax
// (identical results); each accumulates only its d-half: o[4] f32x16 = 64 AGPR.
// This halves the round-7/8 accumulator footprint that caused scratch spill
// (WRITE_SIZE 64.5 MB vs 16.7 MB output).
// Merge: two parallel 4-phase facc chains (disjoint d columns); M/denominator
// over streams 0..3 only (pair stats identical — all-8 would double-count l).
__global__ __launch_bounds__(512, 2) void attn_kernel(const u16* __restrict__ qkv,
                                                      const u16* __restrict__ kfrag,
                                                      const u16* __restrict__ vfrag,
                                                      float* __restrict__ out) {
  __shared__ __align__(16) u16 qlds[16 * 512];  // [t16][lane][8], pre-scaled 1/256
  __shared__ float facc[32][264];
  __shared__ float sm[4][32];
  __shared__ float sl[4][32];

  int tid = threadIdx.x;
  int w = tid >> 6, l = tid & 63;
  int ql = l & 31, hi = l >> 5;
  int stream = w & 3, dhalf = w >> 2;
  int bid = blockIdx.x;
  int b = bid & 7;
  int p = bid >> 3;

  for (int tile = 0; tile < 2; tile++) {
    int jt = tile ? p : (63 - p);
    int q0 = jt * 32;

    // ---- stage Q B-frags (scaled 1/256) into LDS: 1024 frags, 512 thr x 2 ----
    if (tile) __syncthreads();
#pragma unroll
    for (int c = 0; c < 2; c++) {
      int m = c * 512 + tid;
      int t16 = m >> 6, ll = m & 63;
      const u16* src = qkv + (size_t)(b * 2048 + q0 + (ll & 31)) * 768 + t16 * 16 + (ll >> 5) * 8;
      union { u16 h[8]; bf16x8 v; } in, ov;
      in.v = *(const bf16x8*)src;
#pragma unroll
      for (int j = 0; j < 8; j++) ov.h[j] = f2bf(bf2f(in.h[j]) * (1.0f / 256.0f));
      *(bf16x8*)&qlds[(t16 * 64 + ll) * 8] = ov.v;
    }
    __syncthreads();

    f32x16 o[4];
#pragma unroll
    for (int d = 0; d < 4; d++)
#pragma unroll
      for (int r = 0; r < 16; r++) o[d][r] = 0.f;
    float mreg = -__builtin_inff(), ell = 0.f;

    for (int jb = stream; jb <= jt; jb += 4) {
      const u16* kb = kfrag + ((size_t)(b * 64 + jb) * 16 * 64 + l) * 8;
      const u16* vb = vfrag + ((size_t)(b * 64 + jb) * 16 * 64 + l) * 8;

      // ---- QK^T: K streamed in 4 groups of 4; Q from LDS per MFMA ----
      f32x16 sA, sB;
#pragma unroll
      for (int r = 0; r < 16; r++) { sA[r] = 0.f; sB[r] = 0.f; }
#pragma unroll
      for (int g = 0; g < 4; g++) {
        bf16x8 k0 = *(const bf16x8*)(kb + (g * 4 + 0) * 512);
        bf16x8 k1 = *(const bf16x8*)(kb + (g * 4 + 1) * 512);
        bf16x8 k2 = *(const bf16x8*)(kb + (g * 4 + 2) * 512);
        bf16x8 k3 = *(const bf16x8*)(kb + (g * 4 + 3) * 512);
        bf16x8 q0f = *(const bf16x8*)&qlds[((g * 4 + 0) * 64 + l) * 8];
        bf16x8 q1f = *(const bf16x8*)&qlds[((g * 4 + 1) * 64 + l) * 8];
        bf16x8 q2f = *(const bf16x8*)&qlds[((g * 4 + 2) * 64 + l) * 8];
        bf16x8 q3f = *(const bf16x8*)&qlds[((g * 4 + 3) * 64 + l) * 8];
        sA = __builtin_amdgcn_mfma_f32_32x32x16_bf16(k0, q0f, sA, 0, 0, 0);
        sB = __builtin_amdgcn_mfma_f32_32x32x16_bf16(k1, q1f, sB, 0, 0, 0);
        sA = __builtin_amdgcn_mfma_f32_32x32x16_bf16(k2, q2f, sA, 0, 0, 0);
        sB = __builtin_amdgcn_mfma_f32_32x32x16_bf16(k3, q3f, sB, 0, 0, 0);
      }

      // ---- this wave's 8 V frags (its d-half), issued early ----
      bf16x8 ve0[4], ve1[4];
#pragma unroll
      for (int dd = 0; dd < 4; dd++) {
        ve0[dd] = *(const bf16x8*)(vb + (dhalf * 4 + dd) * 512);        // ch 0
        ve1[dd] = *(const bf16x8*)(vb + (8 + dhalf * 4 + dd) * 512);    // ch 1
      }

      float s[16];
#pragma unroll
      for (int r = 0; r < 16; r++) s[r] = sA[r] + sB[r];

      // causal mask (diagonal tile); lane's kv for reg r: (r&3)+8*(r>>2)+4*hi
      if (jb == jt) {
#pragma unroll
        for (int r = 0; r < 16; r++) {
          int kv = (r & 3) + 8 * (r >> 2) + 4 * hi;
          if (kv > ql) s[r] = -__builtin_inff();
        }
      }

      // ---- in-lane online softmax; cross-half via permlane32_swap ----
      float mx = s[0];
#pragma unroll
      for (int r = 1; r < 16; r++) mx = fmaxf(mx, s[r]);
      mx = red_max32(mx);
      if (__any(mx > mreg + 8.f)) {
        float mnew = fmaxf(mreg, mx);
        float sf = __expf(mreg - mnew);
        mreg = mnew;
        ell *= sf;
#pragma unroll
        for (int d = 0; d < 4; d++)
#pragma unroll
          for (int r = 0; r < 16; r++) o[d][r] *= sf;
      }
      float pr[16], ps = 0.f;
#pragma unroll
      for (int r = 0; r < 16; r++) { pr[r] = __expf(s[r] - mreg); ps += pr[r]; }
      ell += red_sum32(ps);

      // ---- pack P -> bf16 words; 4 permlane swaps build both B-frags ----
      u32 wv[8];
#pragma unroll
      for (int i = 0; i < 8; i++) wv[i] = pk2(pr[2 * i], pr[2 * i + 1]);
      pl32pair(wv[0], wv[2]); pl32pair(wv[1], wv[3]);
      pl32pair(wv[4], wv[6]); pl32pair(wv[5], wv[7]);
      union { u32 u[4]; bf16x8 v; } B0, B1;
      B0.u[0] = wv[0]; B0.u[1] = wv[1]; B0.u[2] = wv[2]; B0.u[3] = wv[3];
      B1.u[0] = wv[4]; B1.u[1] = wv[5]; B1.u[2] = wv[6]; B1.u[3] = wv[7];

      // ---- PV for this d-half: o[dd] += V^T(ch0)*P0 + V^T(ch1)*P1 ----
#pragma unroll
      for (int dd = 0; dd < 4; dd++) {
        o[dd] = __builtin_amdgcn_mfma_f32_32x32x16_bf16(ve0[dd], B0.v, o[dd], 0, 0, 0);
        o[dd] = __builtin_amdgcn_mfma_f32_32x32x16_bf16(ve1[dd], B1.v, o[dd], 0, 0, 0);
      }
    }

    // ---- merge: stats from streams 0..3 (waves 4..7 are duplicates) ----
    __syncthreads();
    if (w < 4 && l < 32) { sm[w][l] = mreg; sl[w][l] = ell; }
    __syncthreads();

    float M = fmaxf(fmaxf(sm[0][ql], sm[1][ql]), fmaxf(sm[2][ql], sm[3][ql]));
    float alpha = __expf(mreg - M);

    // two parallel 4-phase chains (d-halves write disjoint facc columns)
#pragma unroll
    for (int ph = 0; ph < 4; ph++) {
      if (stream == ph) {
#pragma unroll
        for (int dd = 0; dd < 4; dd++)
#pragma unroll
          for (int rq = 0; rq < 4; rq++) {
            int base = (dhalf * 4 + dd) * 32 + 8 * rq + 4 * hi;
            f32x4 v;
#pragma unroll
            for (int i = 0; i < 4; i++) v[i] = alpha * o[dd][rq * 4 + i];
            float* fp = &facc[ql][base];
            if (ph == 0) *(f32x4*)fp = v;
            else {
              f32x4 old = *(const f32x4*)fp;
              *(f32x4*)fp = old + v;
            }
          }
      }
      __syncthreads();
    }

    // ---- normalize + coalesced write ----
    int r = tid >> 4, lt = tid & 15;
    float Mr = fmaxf(fmaxf(sm[0][r], sm[1][r]), fmaxf(sm[2][r], sm[3][r]));
    float denom = 0.f;
#pragma unroll
    for (int ww = 0; ww < 4; ww++) denom += __expf(sm[ww][r] - Mr) * sl[ww][r];
    float inv = 1.0f / denom;
    float* orow = out + (size_t)(b * 2048 + q0 + r) * 256;
#pragma unroll
    for (int j = 0; j < 4; j++) {
      int c = (lt + j * 16) * 4;
      f32x4 v = *(const f32x4*)&facc[r][c];
      v[0] *= inv; v[1] *= inv; v[2] *= inv; v[3] *= inv;
      *(f32x4*)&orow[c] = v;
    }
  }
}

extern "C" void kernel_launch(void* const* d_in, const int* in_sizes, int n_in,
                              void* d_out, int out_size, void* d_ws, size_t ws_size,
                              hipStream_t stream) {
  (void)in_sizes; (void)n_in; (void)out_size; (void)ws_size;
  const float* x = (const float*)d_in[0];
  const float* Wq = (const float*)d_in[1];
  const float* Wk = (const float*)d_in[2];
  const float* Wv = (const float*)d_in[3];
  float* out = (float*)d_out;

  char* ws = (char*)d_ws;
  u16* xb  = (u16*)(ws);                    // [0, 67,108,864)
  u16* wbt = (u16*)(ws + 67108864);         // [67,108,864, 70,254,592)
  u16* qkv = (u16*)(ws + 70254592);         // [70,254,592, 95,420,416)
  u16* kfrag = (u16*)(ws);                  // aliases dead xb region
  u16* vfrag = (u16*)(ws + 8388608);

  cast_x_kernel<<<16384, 256, 0, stream>>>(x, xb);
  cast_w_kernel<<<dim3(64, 8, 3), dim3(32, 8), 0, stream>>>(Wq, Wk, Wv, wbt);
  gemm_kernel<<<192, 512, 0, stream>>>(xb, wbt, qkv);
  kfrag_kernel<<<dim3(64, 8), 256, 0, stream>>>(qkv, kfrag);
  vfrag_kernel<<<dim3(64, 8), 256, 0, stream>>>(qkv, vfrag);
  attn_kernel<<<256, 512, 0, stream>>>(qkv, kfrag, vfrag, out);
}

// Round 10
// 150.319 us; speedup vs baseline: 1.2431x; 1.0530x over previous
//
#include <hip/hip_runtime.h>
#include <hip/hip_bf16.h>

typedef unsigned short u16;
typedef unsigned int u32;
typedef __attribute__((ext_vector_type(8))) __bf16 bf16x8;
typedef __attribute__((ext_vector_type(4))) float f32x4;
typedef __attribute__((ext_vector_type(16))) float f32x16;
typedef __attribute__((ext_vector_type(2))) unsigned u32x2;

// f32 -> bf16 round-to-nearest-even
__device__ __forceinline__ u16 f2bf(float f) {
  u32 u = __builtin_bit_cast(u32, f);
  return (u16)((u + 0x7fffu + ((u >> 16) & 1u)) >> 16);
}
__device__ __forceinline__ float bf2f(u16 h) {
  u32 u = ((u32)h) << 16;
  return __builtin_bit_cast(float, u);
}
// pack two floats to bf16x2 word
__device__ __forceinline__ u32 pk2(float lo, float hi) {
  union { __bf16 b[2]; u32 u; } r;
  r.b[0] = (__bf16)lo; r.b[1] = (__bf16)hi;
  return r.u;
}

// permlane32_swap intrinsic wrapper (round-5 post-mortem: never raw asm with
// "+v","+v" on same-value operands — allocator may merge them).
__device__ __forceinline__ void pl32pair(u32& a, u32& b) {
#if __has_builtin(__builtin_amdgcn_permlane32_swap)
  u32x2 r = __builtin_amdgcn_permlane32_swap(a, b, 0, 0);
  a = r.x; b = r.y;
#else
  int hi = (int)((threadIdx.x & 63) >> 5);
  u32 as = __shfl_xor(a, 32), bs = __shfl_xor(b, 32);
  u32 na = hi ? bs : a;
  u32 nb = hi ? b : as;
  a = na; b = nb;
#endif
}
__device__ __forceinline__ float red_max32(float x) {
  u32 a = __builtin_bit_cast(u32, x), b = __builtin_bit_cast(u32, x);
  pl32pair(a, b);
  return fmaxf(__builtin_bit_cast(float, a), __builtin_bit_cast(float, b));
}
__device__ __forceinline__ float red_sum32(float x) {
  u32 a = __builtin_bit_cast(u32, x), b = __builtin_bit_cast(u32, x);
  pl32pair(a, b);
  return __builtin_bit_cast(float, a) + __builtin_bit_cast(float, b);
}

// ---------------- cast x: fp32 -> bf16, 8 elems/thread ----------------
__global__ __launch_bounds__(256) void cast_x_kernel(const float* __restrict__ x,
                                                     u16* __restrict__ xb) {
  size_t i = ((size_t)blockIdx.x * 256 + threadIdx.x) * 8;
  float4 a = *(const float4*)(x + i);
  float4 b = *(const float4*)(x + i + 4);
  union { u16 h[8]; uint4 v; } o;
  o.h[0] = f2bf(a.x); o.h[1] = f2bf(a.y); o.h[2] = f2bf(a.z); o.h[3] = f2bf(a.w);
  o.h[4] = f2bf(b.x); o.h[5] = f2bf(b.y); o.h[6] = f2bf(b.z); o.h[7] = f2bf(b.w);
  *(uint4*)(xb + i) = o.v;
}

// ---------- cast + transpose W: [2048][256] f32 -> Wbt[768][2048] bf16 ----------
__global__ void cast_w_kernel(const float* __restrict__ Wq, const float* __restrict__ Wk,
                              const float* __restrict__ Wv, u16* __restrict__ wbt) {
  __shared__ float tile[32][33];
  int e0 = blockIdx.x * 32, d0 = blockIdx.y * 32, w = blockIdx.z;
  const float* W = (w == 0) ? Wq : ((w == 1) ? Wk : Wv);
  int x = threadIdx.x, y = threadIdx.y;
#pragma unroll
  for (int j = 0; j < 4; j++)
    tile[y + j * 8][x] = W[(size_t)(e0 + y + j * 8) * 256 + d0 + x];
  __syncthreads();
#pragma unroll
  for (int j = 0; j < 4; j++)
    wbt[(size_t)(w * 256 + d0 + y + j * 8) * 2048 + e0 + x] = f2bf(tile[x][y + j * 8]);
}

// ------- GEMM v3: 128x192 tiles, 512 blocks (2/CU), 1 barrier/K-step -------
// qkv[16384][768] = xb[16384][2048] * Wbt[768][2048]^T
// 256 threads (4 waves: 2M x 2N -> per-wave 64x96, acc 4x6 f32x4).
// LDS: 3 rotating buffers (A 8KB + B 12KB each) = 60 KB -> 2 blocks/CU.
// Body t: ds_read(10 b128 from buf t%3); STAGE(t+2 -> buf (t+2)%3, 5 loads);
//         lgkmcnt(0)+sched_barrier; setprio(1) 24 MFMA setprio(0);
//         vmcnt(5) [t+1 landed, t+2 in flight]; ONE barrier. Rotate.
// Swizzle: source col ^= ((row&3)*8 elems); read col = (lg ^ (lr&3))*8.
__global__ __launch_bounds__(256, 2) void gemm_kernel(const u16* __restrict__ A,
                                                      const u16* __restrict__ Bt,
                                                      u16* __restrict__ C) {
  __shared__ __align__(16) u16 As[3][4096];  // 128 rows x 32 cols
  __shared__ __align__(16) u16 Bs[3][6144];  // 192 rows x 32 cols

  int tid = threadIdx.x;
  int w = tid >> 6, l = tid & 63;
  int lr = l & 15, lg = l >> 4;
  int wm = w >> 1, wn = w & 1;

  // XCD grouping: xcd pair shares one B col-panel (768 KB, L2-resident).
  int bid = blockIdx.x;
  int xcd = bid & 7;
  int colb = xcd >> 1;                       // 0..3
  int rowb = ((xcd & 1) << 6) + (bid >> 3);  // 0..127
  int row0 = rowb * 128, col0 = colb * 192;

  // staging coords: load c covers row c*64 + w*16 + (l>>2), 16B chunk l&3,
  // source col pre-swizzled by row&3 = (l>>2)&3.
  int garow = w * 16 + (l >> 2);
  int scol = ((l & 3) * 8) ^ (((l >> 2) & 3) * 8);
  const u16* ga = A + (size_t)(row0 + garow) * 2048 + scol;
  const u16* gb = Bt + (size_t)(col0 + garow) * 2048 + scol;

  f32x4 acc[4][6];
#pragma unroll
  for (int m = 0; m < 4; m++)
#pragma unroll
    for (int n = 0; n < 6; n++) acc[m][n] = (f32x4){0.f, 0.f, 0.f, 0.f};

  int rcol = (lg * 8) ^ ((lr & 3) * 8);  // swizzled LDS read col (u16 units)

#define STAGE3(ts, bi)                                                                 \
  {                                                                                    \
    _Pragma("unroll") for (int c = 0; c < 2; c++)                                      \
        __builtin_amdgcn_global_load_lds(                                              \
            (const __attribute__((address_space(1))) void*)(ga + (size_t)c * 64 * 2048 + (ts) * 32), \
            (__attribute__((address_space(3))) void*)&As[bi][(c * 64 + w * 16) * 32], 16, 0, 0); \
    _Pragma("unroll") for (int c = 0; c < 3; c++)                                      \
        __builtin_amdgcn_global_load_lds(                                              \
            (const __attribute__((address_space(1))) void*)(gb + (size_t)c * 64 * 2048 + (ts) * 32), \
            (__attribute__((address_space(3))) void*)&Bs[bi][(c * 64 + w * 16) * 32], 16, 0, 0); \
  }

  // prologue: tiles 0,1 in flight; wait tile 0 (5 of tile 1 stay outstanding)
  STAGE3(0, 0);
  STAGE3(1, 1);
  asm volatile("s_waitcnt vmcnt(5)" ::: "memory");
  __builtin_amdgcn_s_barrier();

  int bi = 0, bp = 2;
  for (int t = 0; t < 64; t++) {
    int ts = (t + 2 <= 63) ? (t + 2) : 63;  // clamped (uniform load counts)
    const u16* asb = As[bi];
    const u16* bsb = Bs[bi];

    bf16x8 af[4], bfr[6];
#pragma unroll
    for (int m = 0; m < 4; m++)
      af[m] = *(const bf16x8*)&asb[(wm * 64 + m * 16 + lr) * 32 + rcol];
#pragma unroll
    for (int n = 0; n < 6; n++)
      bfr[n] = *(const bf16x8*)&bsb[(wn * 96 + n * 16 + lr) * 32 + rcol];

    STAGE3(ts, bp);

    asm volatile("s_waitcnt lgkmcnt(0)" ::: "memory");
    __builtin_amdgcn_sched_barrier(0);
    __builtin_amdgcn_s_setprio(1);
#pragma unroll
    for (int m = 0; m < 4; m++)
#pragma unroll
      for (int n = 0; n < 6; n++)
        acc[m][n] = __builtin_amdgcn_mfma_f32_16x16x32_bf16(af[m], bfr[n], acc[m][n], 0, 0, 0);
    __builtin_amdgcn_s_setprio(0);

    asm volatile("s_waitcnt vmcnt(5)" ::: "memory");  // t+1 landed; t+2 in flight
    __builtin_amdgcn_s_barrier();

    bi = (bi == 2) ? 0 : bi + 1;
    bp = (bp == 2) ? 0 : bp + 1;
  }
#undef STAGE3

  // C write: col = lane&15, row = (lane>>4)*4 + i (m89-verified)
  int crow = row0 + wm * 64;
  int ccol = col0 + wn * 96 + lr;
#pragma unroll
  for (int m = 0; m < 4; m++)
#pragma unroll
    for (int n = 0; n < 6; n++)
#pragma unroll
      for (int i = 0; i < 4; i++)
        C[(size_t)(crow + m * 16 + lg * 4 + i) * 768 + ccol + n * 16] = f2bf(acc[m][n][i]);
}

// -------- K -> swapped-A-frag order for mfma_32x32x16 --------
__global__ __launch_bounds__(256) void kfrag_kernel(const u16* __restrict__ qkv,
                                                    u16* __restrict__ kfrag) {
  __shared__ __align__(16) u16 tile[32 * 264];
  int t = threadIdx.x, kvb = blockIdx.x, b = blockIdx.y;
#pragma unroll
  for (int c = 0; c < 4; c++) {
    int m = c * 256 + t;
    int r = m >> 5, c16 = m & 31;
    bf16x8 v = *(const bf16x8*)(qkv + (size_t)(b * 2048 + kvb * 32 + r) * 768 + 256 + c16 * 8);
    *(bf16x8*)&tile[r * 264 + c16 * 8] = v;
  }
  __syncthreads();
#pragma unroll
  for (int c = 0; c < 4; c++) {
    int m = c * 256 + t;
    int t16 = m >> 6, l = m & 63;
    bf16x8 v = *(const bf16x8*)&tile[(l & 31) * 264 + t16 * 16 + (l >> 5) * 8];
    *(bf16x8*)(kfrag + ((size_t)((b * 64 + kvb) * 16 + t16) * 64 + l) * 8) = v;
  }
}

// -------- V -> V^T A-frag order for PV mfma_32x32x16 --------
__global__ __launch_bounds__(256) void vfrag_kernel(const u16* __restrict__ qkv,
                                                    u16* __restrict__ vfrag) {
  __shared__ __align__(16) u16 tile[32 * 264];
  int t = threadIdx.x, kvb = blockIdx.x, b = blockIdx.y;
#pragma unroll
  for (int c = 0; c < 4; c++) {
    int m = c * 256 + t;
    int r = m >> 5, c16 = m & 31;
    bf16x8 v = *(const bf16x8*)(qkv + (size_t)(b * 2048 + kvb * 32 + r) * 768 + 512 + c16 * 8);
    *(bf16x8*)&tile[r * 264 + c16 * 8] = v;
  }
  __syncthreads();
#pragma unroll
  for (int c = 0; c < 4; c++) {
    int m = c * 256 + t;
    int ch = m >> 9, dblk = (m >> 6) & 7, l = m & 63;
    union { u16 h[8]; uint4 v; } o;
#pragma unroll
    for (int j = 0; j < 8; j++)
      o.h[j] = tile[(ch * 16 + (l >> 5) * 8 + j) * 264 + dblk * 32 + (l & 31)];
    *(uint4*)(vfrag + ((size_t)(((b * 64 + kvb) * 2 + ch) * 8 + dblk) * 64 + l) * 8) = o.v;
  }
}

// -------- flash attention v8: d-split wave pairs (passing; unchanged) --------
__global__ __launch_bounds__(512, 2) void attn_kernel(const u16* __restrict__ qkv,
                                                      const u16* __restrict__ kfrag,
                                                      const u16* __restrict__ vfrag,
                                                      float* __restrict__ out) {
  __shared__ __align__(16) u16 qlds[16 * 512];
  __shared__ float facc[32][264];
  __shared__ float sm[4][32];
  __shared__ float sl[4][32];

  int tid = threadIdx.x;
  int w = tid >> 6, l = tid & 63;
  int ql = l & 31, hi = l >> 5;
  int stream = w & 3, dhalf = w >> 2;
  int bid = blockIdx.x;
  int b = bid & 7;
  int p = bid >> 3;

  for (int tile = 0; tile < 2; tile++) {
    int jt = tile ? p : (63 - p);
    int q0 = jt * 32;

    if (tile) __syncthreads();
#pragma unroll
    for (int c = 0; c < 2; c++) {
      int m = c * 512 + tid;
      int t16 = m >> 6, ll = m & 63;
      const u16* src = qkv + (size_t)(b * 2048 + q0 + (ll & 31)) * 768 + t16 * 16 + (ll >> 5) * 8;
      union { u16 h[8]; bf16x8 v; } in, ov;
      in.v = *(const bf16x8*)src;
#pragma unroll
      for (int j = 0; j < 8; j++) ov.h[j] = f2bf(bf2f(in.h[j]) * (1.0f / 256.0f));
      *(bf16x8*)&qlds[(t16 * 64 + ll) * 8] = ov.v;
    }
    __syncthreads();

    f32x16 o[4];
#pragma unroll
    for (int d = 0; d < 4; d++)
#pragma unroll
      for (int r = 0; r < 16; r++) o[d][r] = 0.f;
    float mreg = -__builtin_inff(), ell = 0.f;

    for (int jb = stream; jb <= jt; jb += 4) {
      const u16* kb = kfrag + ((size_t)(b * 64 + jb) * 16 * 64 + l) * 8;
      const u16* vb = vfrag + ((size_t)(b * 64 + jb) * 16 * 64 + l) * 8;

      f32x16 sA, sB;
#pragma unroll
      for (int r = 0; r < 16; r++) { sA[r] = 0.f; sB[r] = 0.f; }
#pragma unroll
      for (int g = 0; g < 4; g++) {
        bf16x8 k0 = *(const bf16x8*)(kb + (g * 4 + 0) * 512);
        bf16x8 k1 = *(const bf16x8*)(kb + (g * 4 + 1) * 512);
        bf16x8 k2 = *(const bf16x8*)(kb + (g * 4 + 2) * 512);
        bf16x8 k3 = *(const bf16x8*)(kb + (g * 4 + 3) * 512);
        bf16x8 q0f = *(const bf16x8*)&qlds[((g * 4 + 0) * 64 + l) * 8];
        bf16x8 q1f = *(const bf16x8*)&qlds[((g * 4 + 1) * 64 + l) * 8];
        bf16x8 q2f = *(const bf16x8*)&qlds[((g * 4 + 2) * 64 + l) * 8];
        bf16x8 q3f = *(const bf16x8*)&qlds[((g * 4 + 3) * 64 + l) * 8];
        sA = __builtin_amdgcn_mfma_f32_32x32x16_bf16(k0, q0f, sA, 0, 0, 0);
        sB = __builtin_amdgcn_mfma_f32_32x32x16_bf16(k1, q1f, sB, 0, 0, 0);
        sA = __builtin_amdgcn_mfma_f32_32x32x16_bf16(k2, q2f, sA, 0, 0, 0);
        sB = __builtin_amdgcn_mfma_f32_32x32x16_bf16(k3, q3f, sB, 0, 0, 0);
      }

      bf16x8 ve0[4], ve1[4];
#pragma unroll
      for (int dd = 0; dd < 4; dd++) {
        ve0[dd] = *(const bf16x8*)(vb + (dhalf * 4 + dd) * 512);
        ve1[dd] = *(const bf16x8*)(vb + (8 + dhalf * 4 + dd) * 512);
      }

      float s[16];
#pragma unroll
      for (int r = 0; r < 16; r++) s[r] = sA[r] + sB[r];

      if (jb == jt) {
#pragma unroll
        for (int r = 0; r < 16; r++) {
          int kv = (r & 3) + 8 * (r >> 2) + 4 * hi;
          if (kv > ql) s[r] = -__builtin_inff();
        }
      }

      float mx = s[0];
#pragma unroll
      for (int r = 1; r < 16; r++) mx = fmaxf(mx, s[r]);
      mx = red_max32(mx);
      if (__any(mx > mreg + 8.f)) {
        float mnew = fmaxf(mreg, mx);
        float sf = __expf(mreg - mnew);
        mreg = mnew;
        ell *= sf;
#pragma unroll
        for (int d = 0; d < 4; d++)
#pragma unroll
          for (int r = 0; r < 16; r++) o[d][r] *= sf;
      }
      float pr[16], ps = 0.f;
#pragma unroll
      for (int r = 0; r < 16; r++) { pr[r] = __expf(s[r] - mreg); ps += pr[r]; }
      ell += red_sum32(ps);

      u32 wv[8];
#pragma unroll
      for (int i = 0; i < 8; i++) wv[i] = pk2(pr[2 * i], pr[2 * i + 1]);
      pl32pair(wv[0], wv[2]); pl32pair(wv[1], wv[3]);
      pl32pair(wv[4], wv[6]); pl32pair(wv[5], wv[7]);
      union { u32 u[4]; bf16x8 v; } B0, B1;
      B0.u[0] = wv[0]; B0.u[1] = wv[1]; B0.u[2] = wv[2]; B0.u[3] = wv[3];
      B1.u[0] = wv[4]; B1.u[1] = wv[5]; B1.u[2] = wv[6]; B1.u[3] = wv[7];

#pragma unroll
      for (int dd = 0; dd < 4; dd++) {
        o[dd] = __builtin_amdgcn_mfma_f32_32x32x16_bf16(ve0[dd], B0.v, o[dd], 0, 0, 0);
        o[dd] = __builtin_amdgcn_mfma_f32_32x32x16_bf16(ve1[dd], B1.v, o[dd], 0, 0, 0);
      }
    }

    __syncthreads();
    if (w < 4 && l < 32) { sm[w][l] = mreg; sl[w][l] = ell; }
    __syncthreads();

    float M = fmaxf(fmaxf(sm[0][ql], sm[1][ql]), fmaxf(sm[2][ql], sm[3][ql]));
    float alpha = __expf(mreg - M);

#pragma unroll
    for (int ph = 0; ph < 4; ph++) {
      if (stream == ph) {
#pragma unroll
        for (int dd = 0; dd < 4; dd++)
#pragma unroll
          for (int rq = 0; rq < 4; rq++) {
            int base = (dhalf * 4 + dd) * 32 + 8 * rq + 4 * hi;
            f32x4 v;
#pragma unroll
            for (int i = 0; i < 4; i++) v[i] = alpha * o[dd][rq * 4 + i];
            float* fp = &facc[ql][base];
            if (ph == 0) *(f32x4*)fp = v;
            else {
              f32x4 old = *(const f32x4*)fp;
              *(f32x4*)fp = old + v;
            }
          }
      }
      __syncthreads();
    }

    int r = tid >> 4, lt = tid & 15;
    float Mr = fmaxf(fmaxf(sm[0][r], sm[1][r]), fmaxf(sm[2][r], sm[3][r]));
    float denom = 0.f;
#pragma unroll
    for (int ww = 0; ww < 4; ww++) denom += __expf(sm[ww][r] - Mr) * sl[ww][r];
    float inv = 1.0f / denom;
    float* orow = out + (size_t)(b * 2048 + q0 + r) * 256;
#pragma unroll
    for (int j = 0; j < 4; j++) {
      int c = (lt + j * 16) * 4;
      f32x4 v = *(const f32x4*)&facc[r][c];
      v[0] *= inv; v[1] *= inv; v[2] *= inv; v[3] *= inv;
      *(f32x4*)&orow[c] = v;
    }
  }
}

extern "C" void kernel_launch(void* const* d_in, const int* in_sizes, int n_in,
                              void* d_out, int out_size, void* d_ws, size_t ws_size,
                              hipStream_t stream) {
  (void)in_sizes; (void)n_in; (void)out_size; (void)ws_size;
  const float* x = (const float*)d_in[0];
  const float* Wq = (const float*)d_in[1];
  const float* Wk = (const float*)d_in[2];
  const float* Wv = (const float*)d_in[3];
  float* out = (float*)d_out;

  char* ws = (char*)d_ws;
  u16* xb  = (u16*)(ws);                    // [0, 67,108,864)
  u16* wbt = (u16*)(ws + 67108864);         // [67,108,864, 70,254,592)
  u16* qkv = (u16*)(ws + 70254592);         // [70,254,592, 95,420,416)
  u16* kfrag = (u16*)(ws);                  // aliases dead xb region
  u16* vfrag = (u16*)(ws + 8388608);

  cast_x_kernel<<<16384, 256, 0, stream>>>(x, xb);
  cast_w_kernel<<<dim3(64, 8, 3), dim3(32, 8), 0, stream>>>(Wq, Wk, Wv, wbt);
  gemm_kernel<<<512, 256, 0, stream>>>(xb, wbt, qkv);
  kfrag_kernel<<<dim3(64, 8), 256, 0, stream>>>(qkv, kfrag);
  vfrag_kernel<<<dim3(64, 8), 256, 0, stream>>>(qkv, vfrag);
  attn_kernel<<<256, 512, 0, stream>>>(qkv, kfrag, vfrag, out);
}